// Round 1
// baseline (813.029 us; speedup 1.0000x reference)
//
#include <hip/hip_runtime.h>
#include <math.h>

// Problem constants (from reference)
#define BATCH 16384
#define PP    208      // ids per row (26 features * 8 slots)
#define NF    26       // feature categories
#define VPF   50000u   // vocab per feature
#define EMB   32       // embed dim
#define DD    832      // NF * EMB

// ---------------------------------------------------------------------------
// Kernel A: fused embedding gather + per-category segment sum (pooling).
// Block = 256 threads = 4 waves; each wave handles 2 rows (half-wave per row,
// 32 lanes = 32 embed dims). Each lane exclusively owns (row, e) across all
// categories -> LDS atomicAdd never collides across lanes in one instr, and
// bank aliasing is only 2-way (free).
// ---------------------------------------------------------------------------
__global__ __launch_bounds__(256) void pool_kernel(const int* __restrict__ x,
                                                   const float* __restrict__ table,
                                                   float* __restrict__ feats) {
    __shared__ int   s_ids[8 * PP];   // 8 rows of ids
    __shared__ float s_pool[8 * DD];  // 8 rows of pooled features

    const int tid  = threadIdx.x;
    const int row0 = blockIdx.x * 8;

    for (int i = tid; i < 8 * DD; i += 256) s_pool[i] = 0.0f;
    for (int i = tid; i < 8 * PP; i += 256) s_ids[i] = x[(size_t)row0 * PP + i];
    __syncthreads();

    const int wave = tid >> 6;
    const int lane = tid & 63;
    const int sub  = lane >> 5;   // which row of the pair
    const int e    = lane & 31;   // embed dim
    const int r    = wave * 2 + sub;   // 0..7 row within block

    float*     pool = s_pool + r * DD + e;
    const int* ids  = s_ids + r * PP;

#pragma unroll 4
    for (int p = 0; p < PP; ++p) {
        const unsigned id  = (unsigned)ids[p];          // LDS broadcast
        const unsigned cat = id / VPF;                  // magic-mul div
        const float    v   = table[(size_t)id * EMB + e]; // 128B coalesced / half-wave
        atomicAdd(pool + cat * EMB, v);                 // ds_add_f32
    }
    __syncthreads();

    for (int i = tid; i < 8 * DD; i += 256)
        feats[(size_t)row0 * DD + i] = s_pool[i];
}

// ---------------------------------------------------------------------------
// Kernel B: fused MLP. feats[16384,832] @ W0[832,64] + b0, relu,
// @ W1[64,16] + b1, relu, @ W2[16], sigmoid -> out[16384].
// Block = 256 threads handles TM=64 rows; grid = 256 blocks.
// f32 VALU GEMM with LDS tiles (BK=64), acc 4x4 per thread.
// ---------------------------------------------------------------------------
#define TM 64
#define BK 64

__global__ __launch_bounds__(256) void mlp_kernel(const float* __restrict__ feats,
                                                  const float* __restrict__ W0,
                                                  const float* __restrict__ b0,
                                                  const float* __restrict__ W1,
                                                  const float* __restrict__ b1,
                                                  const float* __restrict__ W2,
                                                  float* __restrict__ out) {
    __shared__ float sF[TM][BK + 1];   // feats tile, +1 pad -> trow conflict-free
    __shared__ float sW[BK][64];       // W0 k-tile
    __shared__ float sH[TM][64 + 1];   // hidden h0
    __shared__ float sW1[64 * 16];
    __shared__ float sB0[64];
    __shared__ float sB1[16];
    __shared__ float sW2[16];

    const int tid  = threadIdx.x;
    const int row0 = blockIdx.x * TM;

    for (int i = tid; i < 64 * 16; i += 256) sW1[i] = W1[i];
    if (tid < 64) sB0[tid] = b0[tid];
    if (tid < 16) sB1[tid] = b1[tid];
    if (tid < 16) sW2[tid] = W2[tid];

    const int tcol = tid & 15;   // 16 col-groups * 4 cols
    const int trow = tid >> 4;   // 16 row-groups * 4 rows

    float acc[4][4];
#pragma unroll
    for (int i = 0; i < 4; ++i)
#pragma unroll
        for (int j = 0; j < 4; ++j) acc[i][j] = 0.0f;

    for (int kt = 0; kt < DD; kt += BK) {
        __syncthreads();  // protect tiles from previous iteration
        for (int i = tid; i < TM * BK; i += 256) {
            const int rr = i >> 6, kk = i & 63;
            sF[rr][kk] = feats[(size_t)(row0 + rr) * DD + kt + kk];
        }
        for (int i = tid; i < BK * 64; i += 256) {
            const int kk = i >> 6, cc = i & 63;
            sW[kk][cc] = W0[(size_t)(kt + kk) * 64 + cc];
        }
        __syncthreads();

#pragma unroll
        for (int k = 0; k < BK; ++k) {
            const float4 wv = *reinterpret_cast<const float4*>(&sW[k][tcol << 2]);
            float f[4];
#pragma unroll
            for (int i = 0; i < 4; ++i) f[i] = sF[trow * 4 + i][k];
#pragma unroll
            for (int i = 0; i < 4; ++i) {
                acc[i][0] = fmaf(f[i], wv.x, acc[i][0]);
                acc[i][1] = fmaf(f[i], wv.y, acc[i][1]);
                acc[i][2] = fmaf(f[i], wv.z, acc[i][2]);
                acc[i][3] = fmaf(f[i], wv.w, acc[i][3]);
            }
        }
    }

    __syncthreads();
#pragma unroll
    for (int i = 0; i < 4; ++i)
#pragma unroll
        for (int j = 0; j < 4; ++j) {
            const int c = (tcol << 2) + j;
            sH[trow * 4 + i][c] = fmaxf(acc[i][j] + sB0[c], 0.0f);
        }
    __syncthreads();

    if (tid < TM) {
        float h1[16];
#pragma unroll
        for (int j = 0; j < 16; ++j) h1[j] = sB1[j];
        for (int k = 0; k < 64; ++k) {
            const float h = sH[tid][k];
#pragma unroll
            for (int j = 0; j < 16; ++j)
                h1[j] = fmaf(h, sW1[k * 16 + j], h1[j]);
        }
        float z = 0.0f;
#pragma unroll
        for (int j = 0; j < 16; ++j)
            z = fmaf(fmaxf(h1[j], 0.0f), sW2[j], z);
        out[row0 + tid] = 1.0f / (1.0f + expf(-z));
    }
}

extern "C" void kernel_launch(void* const* d_in, const int* in_sizes, int n_in,
                              void* d_out, int out_size, void* d_ws, size_t ws_size,
                              hipStream_t stream) {
    const int*   x     = (const int*)d_in[0];
    const float* table = (const float*)d_in[1];
    const float* W0    = (const float*)d_in[2];
    const float* b0    = (const float*)d_in[3];
    const float* W1    = (const float*)d_in[4];
    const float* b1    = (const float*)d_in[5];
    const float* W2    = (const float*)d_in[6];
    float*       out   = (float*)d_out;

    float* feats = (float*)d_ws;  // 16384 * 832 * 4 B = 54.5 MB scratch

    pool_kernel<<<BATCH / 8, 256, 0, stream>>>(x, table, feats);
    mlp_kernel<<<BATCH / TM, 256, 0, stream>>>(feats, W0, b0, W1, b1, W2, out);
}

// Round 2
// 756.094 us; speedup vs baseline: 1.0753x; 1.0753x over previous
//
#include <hip/hip_runtime.h>
#include <math.h>

// Problem constants (from reference)
#define BATCH 16384
#define PP    208      // ids per row (26 features * 8 slots)
#define NF    26       // feature categories
#define VPF   50000u   // vocab per feature
#define EMB   32       // embed dim
#define DD    832      // NF * EMB

typedef __attribute__((ext_vector_type(8))) short short8v;   // 8 bf16 (4 VGPRs)
typedef __attribute__((ext_vector_type(4))) float float4v;   // MFMA C/D frag

static __device__ __forceinline__ ushort f32_to_bf16(float f) {
    unsigned u = __builtin_bit_cast(unsigned, f);
    unsigned r = (u + 0x7fffu + ((u >> 16) & 1u)) >> 16;   // RNE
    return (ushort)r;
}

// ---------------------------------------------------------------------------
// Kernel P: pre-pack W0 (f32 [832][64]) -> bf16 fragment-ordered w0p:
//   w0p[(kt*64 + col)*32 + kk]  with k = kt*32 + kk
// so an MFMA B-fragment load is 16 contiguous bytes per lane.
// ---------------------------------------------------------------------------
__global__ __launch_bounds__(256) void prep_kernel(const float* __restrict__ W0,
                                                   ushort* __restrict__ w0p) {
    const int i = blockIdx.x * 256 + threadIdx.x;
    if (i < DD * 64) {
        const int k = i >> 6, c = i & 63;
        const int kt = k >> 5, kk = k & 31;
        w0p[(kt * 64 + c) * 32 + kk] = f32_to_bf16(W0[i]);
    }
}

// ---------------------------------------------------------------------------
// Kernel A: fused embedding gather + per-category segment sum (pooling).
// One row per block. 256 threads = 8 chunks x 32 embed dims; each chunk
// handles 26 of the 208 ids. Explicit 4-deep load batching for MLP.
// Each lane owns embed dim e exclusively within its chunk; cross-chunk
// collisions on (cat,e) are handled by LDS atomicAdd (bank-conflict-free:
// bank == e). Emits bf16 feats.
// ---------------------------------------------------------------------------
__global__ __launch_bounds__(256, 8) void pool_kernel(const int* __restrict__ x,
                                                      const float* __restrict__ table,
                                                      ushort* __restrict__ feats) {
    __shared__ int   s_ids[PP];
    __shared__ float s_pool[DD];

    const int    tid = threadIdx.x;
    const size_t row = blockIdx.x;

    for (int i = tid; i < DD; i += 256) s_pool[i] = 0.0f;
    if (tid < PP) s_ids[tid] = x[row * PP + tid];
    __syncthreads();

    const int e  = tid & 31;
    const int p0 = (tid >> 5) * 26;      // 8 chunks * 26 ids
    float* pool  = s_pool + e;

#pragma unroll 1
    for (int b = 0; b < 24; b += 4) {
        const unsigned id0 = (unsigned)s_ids[p0 + b + 0];
        const unsigned id1 = (unsigned)s_ids[p0 + b + 1];
        const unsigned id2 = (unsigned)s_ids[p0 + b + 2];
        const unsigned id3 = (unsigned)s_ids[p0 + b + 3];
        const float v0 = table[(size_t)id0 * EMB + e];
        const float v1 = table[(size_t)id1 * EMB + e];
        const float v2 = table[(size_t)id2 * EMB + e];
        const float v3 = table[(size_t)id3 * EMB + e];
        atomicAdd(pool + (id0 / VPF) * EMB, v0);
        atomicAdd(pool + (id1 / VPF) * EMB, v1);
        atomicAdd(pool + (id2 / VPF) * EMB, v2);
        atomicAdd(pool + (id3 / VPF) * EMB, v3);
    }
    {   // tail: ids 24,25 of the chunk
        const unsigned idA = (unsigned)s_ids[p0 + 24];
        const unsigned idB = (unsigned)s_ids[p0 + 25];
        const float vA = table[(size_t)idA * EMB + e];
        const float vB = table[(size_t)idB * EMB + e];
        atomicAdd(pool + (idA / VPF) * EMB, vA);
        atomicAdd(pool + (idB / VPF) * EMB, vB);
    }
    __syncthreads();

    if (tid < DD / 4) {   // 208 threads, 8B packed stores
        ushort4 o;
        o.x = f32_to_bf16(s_pool[tid * 4 + 0]);
        o.y = f32_to_bf16(s_pool[tid * 4 + 1]);
        o.z = f32_to_bf16(s_pool[tid * 4 + 2]);
        o.w = f32_to_bf16(s_pool[tid * 4 + 3]);
        *reinterpret_cast<ushort4*>(feats + row * DD + tid * 4) = o;
    }
}

// ---------------------------------------------------------------------------
// Kernel B: MFMA MLP. h0 = relu(feats_bf16 @ W0_bf16 + b0) via
// mfma_f32_16x16x32_bf16 (fp32 accum), then f32 64->16 relu -> 16->1 sigmoid.
// Block = 256 threads = 4 waves; each wave owns 16 rows x 64 cols
// (4 n-tiles, 26 k-steps). Grid = 256 blocks (64 rows each).
// Frag layout (m89/m91-verified): A: row=lane&15, k=(lane>>4)*8+j;
// B: col=lane&15, same k; C: row=(lane>>4)*4+reg, col=lane&15.
// ---------------------------------------------------------------------------
__global__ __launch_bounds__(256) void mlp_kernel(const ushort* __restrict__ feats,
                                                  const ushort* __restrict__ w0p,
                                                  const float* __restrict__ b0,
                                                  const float* __restrict__ W1,
                                                  const float* __restrict__ b1,
                                                  const float* __restrict__ W2,
                                                  float* __restrict__ out) {
    __shared__ float sH[64][65];    // h0, +1 pad
    __shared__ float sH1[64][17];   // h1

    const int tid   = threadIdx.x;
    const int wave  = tid >> 6;
    const int lane  = tid & 63;
    const int lrow  = lane & 15;
    const int lk    = lane >> 4;
    const int brow0 = blockIdx.x * 64;

    float4v acc[4];
#pragma unroll
    for (int n = 0; n < 4; ++n) acc[n] = (float4v){0.f, 0.f, 0.f, 0.f};

    const ushort* frow  = feats + (size_t)(brow0 + wave * 16 + lrow) * DD + lk * 8;
    const ushort* wbase = w0p + lrow * 32 + lk * 8;

#pragma unroll 2
    for (int kt = 0; kt < 26; ++kt) {
        const short8v a = *reinterpret_cast<const short8v*>(frow + kt * 32);
#pragma unroll
        for (int n = 0; n < 4; ++n) {
            const short8v b = *reinterpret_cast<const short8v*>(wbase + (size_t)(kt * 64 + n * 16) * 32);
            acc[n] = __builtin_amdgcn_mfma_f32_16x16x32_bf16(a, b, acc[n], 0, 0, 0);
        }
    }

#pragma unroll
    for (int n = 0; n < 4; ++n) {
        const int   col = n * 16 + lrow;
        const float bb  = b0[col];
#pragma unroll
        for (int r = 0; r < 4; ++r) {
            const int rr = wave * 16 + lk * 4 + r;
            sH[rr][col] = fmaxf(acc[n][r] + bb, 0.f);
        }
    }
    __syncthreads();

    {   // h1 = relu(h0 @ W1 + b1): 64 rows x 16 cols, thread = (row, 4-col group)
        const int r = tid >> 2, cg = (tid & 3) * 4;
        float a0 = b1[cg + 0], a1 = b1[cg + 1], a2 = b1[cg + 2], a3 = b1[cg + 3];
#pragma unroll 8
        for (int k = 0; k < 64; ++k) {
            const float  h  = sH[r][k];
            const float4 wv = *reinterpret_cast<const float4*>(W1 + k * 16 + cg);
            a0 = fmaf(h, wv.x, a0);
            a1 = fmaf(h, wv.y, a1);
            a2 = fmaf(h, wv.z, a2);
            a3 = fmaf(h, wv.w, a3);
        }
        sH1[r][cg + 0] = fmaxf(a0, 0.f);
        sH1[r][cg + 1] = fmaxf(a1, 0.f);
        sH1[r][cg + 2] = fmaxf(a2, 0.f);
        sH1[r][cg + 3] = fmaxf(a3, 0.f);
    }
    __syncthreads();

    if (tid < 64) {
        float z = 0.f;
#pragma unroll
        for (int j = 0; j < 16; ++j) z = fmaf(sH1[tid][j], W2[j], z);
        out[brow0 + tid] = 1.f / (1.f + expf(-z));
    }
}

extern "C" void kernel_launch(void* const* d_in, const int* in_sizes, int n_in,
                              void* d_out, int out_size, void* d_ws, size_t ws_size,
                              hipStream_t stream) {
    const int*   x     = (const int*)d_in[0];
    const float* table = (const float*)d_in[1];
    const float* W0    = (const float*)d_in[2];
    const float* b0    = (const float*)d_in[3];
    const float* W1    = (const float*)d_in[4];
    const float* b1    = (const float*)d_in[5];
    const float* W2    = (const float*)d_in[6];
    float*       out   = (float*)d_out;

    ushort* feats16 = (ushort*)d_ws;                       // 16384*832*2 = 27.3 MB
    ushort* w0p     = feats16 + (size_t)BATCH * DD;        // 53248*2 = 106 KB

    prep_kernel<<<(DD * 64 + 255) / 256, 256, 0, stream>>>(W0, w0p);
    pool_kernel<<<BATCH, 256, 0, stream>>>(x, table, feats16);
    mlp_kernel<<<BATCH / 64, 256, 0, stream>>>(feats16, w0p, b0, W1, b1, W2, out);
}